// Round 5
// baseline (406.141 us; speedup 1.0000x reference)
//
#include <hip/hip_runtime.h>
#include <hip/hip_cooperative_groups.h>

namespace cg = cooperative_groups;

#define NSEG   16
#define WROWS  16
#define GBLK   1024
#define BTHR   256
#define SLICES 8      // fallback path

// ================= fused cooperative kernel =================
// Assumes H == BTHR*4 (H=1024): thread t owns float4 column t.
__global__ void __launch_bounds__(BTHR, 4) k_fused(
        const float* __restrict__ x, const int* __restrict__ mask,
        float* __restrict__ out, float* __restrict__ mout,
        int* __restrict__ vlen, float* __restrict__ part,
        int B, int L, int H) {
    cg::grid_group grid = cg::this_grid();
    int bid = blockIdx.x;
    int t = threadIdx.x;

    // ---- phase 1: blocks 0..B-1 reduce their mask row -> vlen ----
    if (bid < B) {
        const int4* m4 = (const int4*)(mask + (size_t)bid * L);
        int n4 = L >> 2;
        int acc = 0;
        for (int i = t; i < n4; i += BTHR) { int4 v = m4[i]; acc += v.x + v.y + v.z + v.w; }
        #pragma unroll
        for (int off = 32; off > 0; off >>= 1) acc += __shfl_down(acc, off, 64);
        __shared__ int sh[4];
        if ((t & 63) == 0) sh[t >> 6] = acc;
        __syncthreads();
        if (t == 0) vlen[bid] = sh[0] + sh[1] + sh[2] + sh[3];
    }
    __threadfence();
    grid.sync();

    int vls[16];
    for (int b = 0; b < B; ++b) vls[b] = vlen[b];
    int nst = B * NSEG;

    // seg_mask outputs (block 0). start = floor(s*vl/16) < vl always for vl>=1.
    if (bid == 0 && t < nst) {
        int b = t >> 4, s = t & 15, vl = vls[b];
        int st = (s * vl) >> 4;
        mout[t] = (st < vl) ? 1.0f : 0.0f;
    }

    // ---- phase 2: prefix-balanced slices of <=WROWS rows -> part[j] ----
    {
        int bs = 0, pre = 0;   // pre = slices before segment bs (monotone scan)
        for (int j = bid; ; j += GBLK) {
            int st = 0, ns = 0;
            while (bs < nst) {
                int vl = vls[bs >> 4], ss = bs & 15;
                st = (ss * vl) >> 4;
                int en = ((ss + 1) * vl) >> 4;
                ns = (st < vl) ? ((en - st) > 0 ? (en - st) : 1) : 0;
                int ms = (ns + WROWS - 1) / WROWS;
                if (j < pre + ms) break;
                pre += ms; ++bs;
            }
            if (bs >= nst) break;
            int lo = j - pre;
            int r0 = st + lo * WROWS;
            int r1 = st + ns; if (r1 > r0 + WROWS) r1 = r0 + WROWS;
            int cr = r1 - r0;

            const float* base = x + ((size_t)(bs >> 4) * L + r0) * H + t * 4;
            float4 a0 = {0,0,0,0}, a1 = {0,0,0,0}, a2 = {0,0,0,0}, a3 = {0,0,0,0};
            int r = 0;
            for (; r + 4 <= cr; r += 4) {
                float4 v0 = *(const float4*)(base + (size_t)(r + 0) * H);
                float4 v1 = *(const float4*)(base + (size_t)(r + 1) * H);
                float4 v2 = *(const float4*)(base + (size_t)(r + 2) * H);
                float4 v3 = *(const float4*)(base + (size_t)(r + 3) * H);
                a0.x += v0.x; a0.y += v0.y; a0.z += v0.z; a0.w += v0.w;
                a1.x += v1.x; a1.y += v1.y; a1.z += v1.z; a1.w += v1.w;
                a2.x += v2.x; a2.y += v2.y; a2.z += v2.z; a2.w += v2.w;
                a3.x += v3.x; a3.y += v3.y; a3.z += v3.z; a3.w += v3.w;
            }
            for (; r < cr; ++r) {
                float4 v0 = *(const float4*)(base + (size_t)r * H);
                a0.x += v0.x; a0.y += v0.y; a0.z += v0.z; a0.w += v0.w;
            }
            float4 o;
            o.x = (a0.x + a1.x) + (a2.x + a3.x);
            o.y = (a0.y + a1.y) + (a2.y + a3.y);
            o.z = (a0.z + a1.z) + (a2.z + a3.z);
            o.w = (a0.w + a1.w) + (a2.w + a3.w);
            *(float4*)(part + (size_t)j * H + t * 4) = o;
        }
    }
    __threadfence();
    grid.sync();

    // ---- phase 3: blocks 0..nst-1 reduce their partial range, scale, write ----
    if (bid < nst) {
        int bs = bid;
        int p0 = 0, m = 0, cnt = 1;
        for (int q = 0; q <= bs; ++q) {
            int vl = vls[q >> 4], ss = q & 15;
            int st = (ss * vl) >> 4;
            int en = ((ss + 1) * vl) >> 4;
            int ns = (st < vl) ? ((en - st) > 0 ? (en - st) : 1) : 0;
            int ms = (ns + WROWS - 1) / WROWS;
            if (q < bs) p0 += ms;
            else { m = ms; cnt = (en - st) > 0 ? (en - st) : 1; }
        }
        float4 acc = {0,0,0,0};
        for (int k = 0; k < m; ++k) {
            float4 v = *(const float4*)(part + (size_t)(p0 + k) * H + t * 4);
            acc.x += v.x; acc.y += v.y; acc.z += v.z; acc.w += v.w;
        }
        float scl = 1.0f / (float)cnt;
        acc.x *= scl; acc.y *= scl; acc.z *= scl; acc.w *= scl;
        *(float4*)(out + (size_t)bs * H + t * 4) = acc;
    }
}

// ================= fallback (proven R2 path) =================
__global__ void __launch_bounds__(256) k_part_fb(
        const float* __restrict__ x, const int* __restrict__ mask,
        float* __restrict__ part, int* __restrict__ vlen,
        float* __restrict__ mout, int L, int H) {
    int id = blockIdx.x;
    int sl = id & (SLICES - 1);
    int bs = id / SLICES;
    int b = bs >> 4, s = bs & 15;
    int t = threadIdx.x;

    const int4* m4 = (const int4*)(mask + (size_t)b * L);
    int n4 = L >> 2;
    int acc = 0;
    for (int i = t; i < n4; i += 256) { int4 v = m4[i]; acc += v.x + v.y + v.z + v.w; }
    #pragma unroll
    for (int off = 32; off > 0; off >>= 1) acc += __shfl_down(acc, off, 64);
    __shared__ int sh[4];
    if ((t & 63) == 0) sh[t >> 6] = acc;
    __syncthreads();
    __shared__ int vsh;
    if (t == 0) {
        int v = sh[0] + sh[1] + sh[2] + sh[3];
        vsh = v;
        if (sl == 0) {
            vlen[b] = v;
            int st = (s * v) >> 4;
            mout[bs] = (st < v) ? 1.0f : 0.0f;
        }
    }
    __syncthreads();
    int vl = vsh;
    int start = (s * vl) >> 4;
    int end   = ((s + 1) * vl) >> 4;
    int n = (start < vl) ? max(end - start, 1) : 0;
    int i0 = (sl * n) / SLICES;
    int i1 = ((sl + 1) * n) / SLICES;
    int cnt = i1 - i0;

    const float* base = x + ((size_t)b * L + start + i0) * H + t * 4;
    float4 a0 = {0,0,0,0}, a1 = {0,0,0,0}, a2 = {0,0,0,0}, a3 = {0,0,0,0};
    int r = 0;
    for (; r + 4 <= cnt; r += 4) {
        float4 v0 = *(const float4*)(base + (size_t)(r + 0) * H);
        float4 v1 = *(const float4*)(base + (size_t)(r + 1) * H);
        float4 v2 = *(const float4*)(base + (size_t)(r + 2) * H);
        float4 v3 = *(const float4*)(base + (size_t)(r + 3) * H);
        a0.x += v0.x; a0.y += v0.y; a0.z += v0.z; a0.w += v0.w;
        a1.x += v1.x; a1.y += v1.y; a1.z += v1.z; a1.w += v1.w;
        a2.x += v2.x; a2.y += v2.y; a2.z += v2.z; a2.w += v2.w;
        a3.x += v3.x; a3.y += v3.y; a3.z += v3.z; a3.w += v3.w;
    }
    for (; r < cnt; ++r) {
        float4 v0 = *(const float4*)(base + (size_t)r * H);
        a0.x += v0.x; a0.y += v0.y; a0.z += v0.z; a0.w += v0.w;
    }
    float4 o;
    o.x = (a0.x + a1.x) + (a2.x + a3.x);
    o.y = (a0.y + a1.y) + (a2.y + a3.y);
    o.z = (a0.z + a1.z) + (a2.z + a3.z);
    o.w = (a0.w + a1.w) + (a2.w + a3.w);
    *(float4*)(part + (size_t)id * H + t * 4) = o;
}

__global__ void k_reduce_fb(const float* __restrict__ part, const int* __restrict__ vlen,
                            float* __restrict__ out, int H) {
    int bs = blockIdx.x;
    int b = bs >> 4, s = bs & 15;
    int vl = vlen[b];
    int start = (s * vl) >> 4;
    int end   = ((s + 1) * vl) >> 4;
    int cnt = max(end - start, 1);
    int hbase = blockIdx.y * 256;
    int lane = threadIdx.x;

    float4 acc = {0,0,0,0};
    #pragma unroll
    for (int sl = 0; sl < SLICES; ++sl) {
        float4 v = *(const float4*)(part + ((size_t)bs * SLICES + sl) * H + hbase + lane * 4);
        acc.x += v.x; acc.y += v.y; acc.z += v.z; acc.w += v.w;
    }
    float scl = 1.0f / (float)cnt;
    acc.x *= scl; acc.y *= scl; acc.z *= scl; acc.w *= scl;
    *(float4*)(out + (size_t)bs * H + hbase + lane * 4) = acc;
}

extern "C" void kernel_launch(void* const* d_in, const int* in_sizes, int n_in,
                              void* d_out, int out_size, void* d_ws, size_t ws_size,
                              hipStream_t stream) {
    const float* hs  = (const float*)d_in[0];
    const int* mask  = (const int*)d_in[1];
    int H = in_sizes[0] / in_sizes[1];          // 1024
    int B = out_size / (NSEG * (H + 1));        // 8
    int L = in_sizes[1] / B;                    // 4096

    float* seg_out  = (float*)d_out;
    float* mask_out = seg_out + (size_t)B * NSEG * H;
    int* vlen = (int*)d_ws;
    float* part = (float*)d_ws + 64;            // 256 B offset, 16B-aligned

    void* args[] = { (void*)&hs, (void*)&mask, (void*)&seg_out, (void*)&mask_out,
                     (void*)&vlen, (void*)&part, (void*)&B, (void*)&L, (void*)&H };
    hipError_t e = hipLaunchCooperativeKernel((const void*)k_fused,
                                              dim3(GBLK), dim3(BTHR),
                                              args, 0, stream);
    if (e != hipSuccess) {
        // fallback: proven 2-kernel path
        k_part_fb<<<B * NSEG * SLICES, 256, 0, stream>>>(hs, mask, part, vlen, mask_out, L, H);
        dim3 gridB(B * NSEG, H / 256);
        k_reduce_fb<<<gridB, 64, 0, stream>>>(part, vlen, seg_out, H);
    }
}

// Round 6
// 193.833 us; speedup vs baseline: 2.0953x; 2.0953x over previous
//
#include <hip/hip_runtime.h>

#define NSEG   16
#define SLICES 8
#define BTHR   256

// Single fused kernel. Grid = B*NSEG*SLICES blocks of 256 threads.
// Each block: (1) redundantly block-reduces its batch's mask row (16 KB,
// L2-resident) -> vl; (2) streams its <=1/8 token-slice of one segment into
// a partial sum in ws; (3) last-arriving block per segment (device-scope
// atomic counter) reduces the 8 partials in FIXED slice order (bitwise
// deterministic) and writes the output. cnt[] is zeroed per call by a
// hipMemsetAsync node before this kernel.
__global__ void __launch_bounds__(BTHR) k_main(
        const float* __restrict__ x, const int* __restrict__ mask,
        float* __restrict__ out, float* __restrict__ mout,
        float* __restrict__ part, int* __restrict__ cnt,
        int L, int H) {
    int id = blockIdx.x;                 // (b*NSEG+s)*SLICES + sl
    int sl = id & (SLICES - 1);
    int bs = id / SLICES;
    int b = bs >> 4, s = bs & 15;
    int t = threadIdx.x;                 // 0..255

    // ---- block-reduce mask row -> vl ----
    const int4* m4 = (const int4*)(mask + (size_t)b * L);
    int n4 = L >> 2;
    int acc = 0;
    for (int i = t; i < n4; i += BTHR) { int4 v = m4[i]; acc += v.x + v.y + v.z + v.w; }
    #pragma unroll
    for (int off = 32; off > 0; off >>= 1) acc += __shfl_down(acc, off, 64);
    __shared__ int sh[4];
    if ((t & 63) == 0) sh[t >> 6] = acc;
    __syncthreads();
    __shared__ int vsh;
    if (t == 0) {
        int v = sh[0] + sh[1] + sh[2] + sh[3];
        vsh = v;
        if (sl == 0) {
            int st = (s * v) >> 4;                    // exact: s*v < 2^24
            mout[bs] = (st < v) ? 1.0f : 0.0f;
        }
    }
    __syncthreads();
    int vl = vsh;

    int start = (s * vl) >> 4;
    int end   = ((s + 1) * vl) >> 4;                  // s==15 -> exactly vl
    int n = (start < vl) ? max(end - start, 1) : 0;   // effective token count
    int segcnt = max(end - start, 1);
    int i0 = (sl * n) / SLICES;
    int i1 = ((sl + 1) * n) / SLICES;
    int rows = i1 - i0;

    // ---- stream rows [start+i0, start+i1), one 4 KB row per block-iter ----
    const float* base = x + ((size_t)b * L + start + i0) * H + t * 4;
    float4 a0 = {0,0,0,0}, a1 = {0,0,0,0}, a2 = {0,0,0,0}, a3 = {0,0,0,0};
    int r = 0;
    for (; r + 4 <= rows; r += 4) {
        float4 v0 = *(const float4*)(base + (size_t)(r + 0) * H);
        float4 v1 = *(const float4*)(base + (size_t)(r + 1) * H);
        float4 v2 = *(const float4*)(base + (size_t)(r + 2) * H);
        float4 v3 = *(const float4*)(base + (size_t)(r + 3) * H);
        a0.x += v0.x; a0.y += v0.y; a0.z += v0.z; a0.w += v0.w;
        a1.x += v1.x; a1.y += v1.y; a1.z += v1.z; a1.w += v1.w;
        a2.x += v2.x; a2.y += v2.y; a2.z += v2.z; a2.w += v2.w;
        a3.x += v3.x; a3.y += v3.y; a3.z += v3.z; a3.w += v3.w;
    }
    for (; r < rows; ++r) {
        float4 v0 = *(const float4*)(base + (size_t)r * H);
        a0.x += v0.x; a0.y += v0.y; a0.z += v0.z; a0.w += v0.w;
    }
    float4 o;
    o.x = (a0.x + a1.x) + (a2.x + a3.x);
    o.y = (a0.y + a1.y) + (a2.y + a3.y);
    o.z = (a0.z + a1.z) + (a2.z + a3.z);
    o.w = (a0.w + a1.w) + (a2.w + a3.w);
    *(float4*)(part + (size_t)id * H + t * 4) = o;

    // ---- publish partial, last block per segment reduces ----
    __threadfence();                      // make this block's writes agent-visible
    __syncthreads();                      // all threads' stores ordered before t0's atomic
    __shared__ int last;
    if (t == 0) {
        int old = __hip_atomic_fetch_add(&cnt[bs], 1, __ATOMIC_ACQ_REL,
                                         __HIP_MEMORY_SCOPE_AGENT);
        last = (old == SLICES - 1);
    }
    __syncthreads();
    if (last) {
        __threadfence();                  // acquire: invalidate stale cached partials
        float4 r4 = {0,0,0,0};
        #pragma unroll
        for (int q = 0; q < SLICES; ++q) {
            float4 v = *(const float4*)(part + ((size_t)bs * SLICES + q) * H + t * 4);
            r4.x += v.x; r4.y += v.y; r4.z += v.z; r4.w += v.w;
        }
        float scl = 1.0f / (float)segcnt; // empty segment -> partials 0 -> writes 0
        r4.x *= scl; r4.y *= scl; r4.z *= scl; r4.w *= scl;
        *(float4*)(out + (size_t)bs * H + t * 4) = r4;
    }
}

extern "C" void kernel_launch(void* const* d_in, const int* in_sizes, int n_in,
                              void* d_out, int out_size, void* d_ws, size_t ws_size,
                              hipStream_t stream) {
    const float* hs  = (const float*)d_in[0];
    const int* mask  = (const int*)d_in[1];
    int H = in_sizes[0] / in_sizes[1];          // 1024
    int B = out_size / (NSEG * (H + 1));        // 8
    int L = in_sizes[1] / B;                    // 4096

    float* seg_out  = (float*)d_out;
    float* mask_out = seg_out + (size_t)B * NSEG * H;
    int* cntr = (int*)d_ws;                     // B*NSEG ints
    float* part = (float*)d_ws + 256;           // 1 KB offset, 16B-aligned

    hipMemsetAsync(cntr, 0, (size_t)B * NSEG * sizeof(int), stream);
    k_main<<<B * NSEG * SLICES, BTHR, 0, stream>>>(hs, mask, seg_out, mask_out,
                                                   part, cntr, L, H);
}

// Round 7
// 31.183 us; speedup vs baseline: 13.0243x; 6.2159x over previous
//
#include <hip/hip_runtime.h>

#define NSEG   16
#define SLICES 8
#define BTHR   256

// Single kernel, no fences, no grid sync. Grid = B*NSEG*SLICES = 1024 blocks.
// Each block: (1) block-reduces its batch's mask row (16 KB, L2-resident) ->
// vl; (2) streams its <=32-row token-slice of one segment, pre-scales by
// 1/cnt; (3) accumulates into d_out via relaxed agent-scope HW f32 atomics
// (global_atomic_add_f32 -- no cache-maintenance ops). d_out's seg region is
// zeroed by a hipMemsetAsync graph node before this kernel. sl==0 blocks
// write the seg_mask floats directly (single writer per value).
__global__ void __launch_bounds__(BTHR) k_main(
        const float* __restrict__ x, const int* __restrict__ mask,
        float* __restrict__ out, float* __restrict__ mout,
        int L, int H) {
    int id = blockIdx.x;                 // (b*NSEG+s)*SLICES + sl
    int sl = id & (SLICES - 1);
    int bs = id / SLICES;
    int b = bs >> 4, s = bs & 15;
    int t = threadIdx.x;                 // 0..255

    // ---- block-reduce mask row -> vl ----
    const int4* m4 = (const int4*)(mask + (size_t)b * L);
    int n4 = L >> 2;
    int acc = 0;
    for (int i = t; i < n4; i += BTHR) { int4 v = m4[i]; acc += v.x + v.y + v.z + v.w; }
    #pragma unroll
    for (int off = 32; off > 0; off >>= 1) acc += __shfl_down(acc, off, 64);
    __shared__ int sh[4];
    if ((t & 63) == 0) sh[t >> 6] = acc;
    __syncthreads();
    __shared__ int vsh;
    if (t == 0) {
        int v = sh[0] + sh[1] + sh[2] + sh[3];
        vsh = v;
        if (sl == 0) {
            int st = (s * v) >> 4;                    // exact: s*v < 2^24
            mout[bs] = (st < v) ? 1.0f : 0.0f;
        }
    }
    __syncthreads();
    int vl = vsh;

    int start = (s * vl) >> 4;
    int end   = ((s + 1) * vl) >> 4;                  // s==15 -> exactly vl
    int n = (start < vl) ? max(end - start, 1) : 0;   // effective token count
    int segcnt = max(end - start, 1);
    int i0 = (sl * n) / SLICES;
    int i1 = ((sl + 1) * n) / SLICES;
    int rows = i1 - i0;                               // <= 32
    if (rows <= 0) return;                            // empty slice: out stays 0

    // ---- stream rows [start+i0, start+i1), one 4 KB row per block-iter ----
    const float* base = x + ((size_t)b * L + start + i0) * H + t * 4;
    float4 a0 = {0,0,0,0}, a1 = {0,0,0,0}, a2 = {0,0,0,0}, a3 = {0,0,0,0};
    float4 a4 = {0,0,0,0}, a5 = {0,0,0,0}, a6 = {0,0,0,0}, a7 = {0,0,0,0};
    int r = 0;
    for (; r + 8 <= rows; r += 8) {
        float4 v0 = *(const float4*)(base + (size_t)(r + 0) * H);
        float4 v1 = *(const float4*)(base + (size_t)(r + 1) * H);
        float4 v2 = *(const float4*)(base + (size_t)(r + 2) * H);
        float4 v3 = *(const float4*)(base + (size_t)(r + 3) * H);
        float4 v4 = *(const float4*)(base + (size_t)(r + 4) * H);
        float4 v5 = *(const float4*)(base + (size_t)(r + 5) * H);
        float4 v6 = *(const float4*)(base + (size_t)(r + 6) * H);
        float4 v7 = *(const float4*)(base + (size_t)(r + 7) * H);
        a0.x += v0.x; a0.y += v0.y; a0.z += v0.z; a0.w += v0.w;
        a1.x += v1.x; a1.y += v1.y; a1.z += v1.z; a1.w += v1.w;
        a2.x += v2.x; a2.y += v2.y; a2.z += v2.z; a2.w += v2.w;
        a3.x += v3.x; a3.y += v3.y; a3.z += v3.z; a3.w += v3.w;
        a4.x += v4.x; a4.y += v4.y; a4.z += v4.z; a4.w += v4.w;
        a5.x += v5.x; a5.y += v5.y; a5.z += v5.z; a5.w += v5.w;
        a6.x += v6.x; a6.y += v6.y; a6.z += v6.z; a6.w += v6.w;
        a7.x += v7.x; a7.y += v7.y; a7.z += v7.z; a7.w += v7.w;
    }
    for (; r < rows; ++r) {
        float4 v0 = *(const float4*)(base + (size_t)r * H);
        a0.x += v0.x; a0.y += v0.y; a0.z += v0.z; a0.w += v0.w;
    }
    float4 o;
    o.x = ((a0.x + a1.x) + (a2.x + a3.x)) + ((a4.x + a5.x) + (a6.x + a7.x));
    o.y = ((a0.y + a1.y) + (a2.y + a3.y)) + ((a4.y + a5.y) + (a6.y + a7.y));
    o.z = ((a0.z + a1.z) + (a2.z + a3.z)) + ((a4.z + a5.z) + (a6.z + a7.z));
    o.w = ((a0.w + a1.w) + (a2.w + a3.w)) + ((a4.w + a5.w) + (a6.w + a7.w));

    float scl = 1.0f / (float)segcnt;
    o.x *= scl; o.y *= scl; o.z *= scl; o.w *= scl;

    float* po = out + (size_t)bs * H + t * 4;
    __hip_atomic_fetch_add(po + 0, o.x, __ATOMIC_RELAXED, __HIP_MEMORY_SCOPE_AGENT);
    __hip_atomic_fetch_add(po + 1, o.y, __ATOMIC_RELAXED, __HIP_MEMORY_SCOPE_AGENT);
    __hip_atomic_fetch_add(po + 2, o.z, __ATOMIC_RELAXED, __HIP_MEMORY_SCOPE_AGENT);
    __hip_atomic_fetch_add(po + 3, o.w, __ATOMIC_RELAXED, __HIP_MEMORY_SCOPE_AGENT);
}

extern "C" void kernel_launch(void* const* d_in, const int* in_sizes, int n_in,
                              void* d_out, int out_size, void* d_ws, size_t ws_size,
                              hipStream_t stream) {
    const float* hs  = (const float*)d_in[0];
    const int* mask  = (const int*)d_in[1];
    int H = in_sizes[0] / in_sizes[1];          // 1024
    int B = out_size / (NSEG * (H + 1));        // 8
    int L = in_sizes[1] / B;                    // 4096

    float* seg_out  = (float*)d_out;
    float* mask_out = seg_out + (size_t)B * NSEG * H;

    // zero the seg-state accumulation region (mask region written directly)
    hipMemsetAsync(seg_out, 0, (size_t)B * NSEG * H * sizeof(float), stream);
    k_main<<<B * NSEG * SLICES, BTHR, 0, stream>>>(hs, mask, seg_out, mask_out, L, H);
}

// Round 8
// 20.687 us; speedup vs baseline: 19.6322x; 1.5074x over previous
//
#include <hip/hip_runtime.h>

#define NSEG   16
#define SLICES 16
#define BTHR   256

// Stage A: grid = B*NSEG*SLICES = 2048 blocks (8/CU), grain <= 16 rows.
// Swizzled so all slices of segment bs land on XCD bs%8 (consecutive
// blockIdx round-robin XCDs), keeping that segment's partials in ONE
// XCD's L2 for the reducer. Each block redundantly reduces its batch's
// mask row (16 KB, L2-hot) -> vl, streams its row-slice, writes one
// 4 KB partial. sl==0 block also writes vlen[b] + seg_mask float.
__global__ void __launch_bounds__(BTHR) k_part(
        const float* __restrict__ x, const int* __restrict__ mask,
        float* __restrict__ part, int* __restrict__ vlen,
        float* __restrict__ mout, int L, int H) {
    int bid = blockIdx.x;
    int x8 = bid & 7, inner = bid >> 3;
    int sl = inner & (SLICES - 1);
    int bs = ((inner >> 4) << 3) + x8;   // bs % 8 == x8  -> XCD co-location
    int b = bs >> 4, s = bs & 15;
    int t = threadIdx.x;                 // 0..255

    // ---- block-reduce mask row -> vl ----
    const int4* m4 = (const int4*)(mask + (size_t)b * L);
    int n4 = L >> 2;
    int acc = 0;
    for (int i = t; i < n4; i += BTHR) { int4 v = m4[i]; acc += v.x + v.y + v.z + v.w; }
    #pragma unroll
    for (int off = 32; off > 0; off >>= 1) acc += __shfl_down(acc, off, 64);
    __shared__ int sh[4];
    if ((t & 63) == 0) sh[t >> 6] = acc;
    __syncthreads();
    __shared__ int vsh;
    if (t == 0) {
        int v = sh[0] + sh[1] + sh[2] + sh[3];
        vsh = v;
        if (sl == 0) {
            vlen[b] = v;                              // 16 identical writers/batch
            int st = (s * v) >> 4;                    // exact: s*v < 2^24
            mout[bs] = (st < v) ? 1.0f : 0.0f;
        }
    }
    __syncthreads();
    int vl = vsh;

    int start = (s * vl) >> 4;
    int end   = ((s + 1) * vl) >> 4;                  // s==15 -> exactly vl
    int n = (start < vl) ? max(end - start, 1) : 0;   // effective token count
    int i0 = (sl * n) / SLICES;
    int i1 = ((sl + 1) * n) / SLICES;
    int rows = i1 - i0;                               // <= 16

    // ---- stream rows [start+i0, start+i1), one 4 KB row per block-iter ----
    const float* base = x + ((size_t)b * L + start + i0) * H + t * 4;
    float4 a0 = {0,0,0,0}, a1 = {0,0,0,0}, a2 = {0,0,0,0}, a3 = {0,0,0,0};
    float4 a4 = {0,0,0,0}, a5 = {0,0,0,0}, a6 = {0,0,0,0}, a7 = {0,0,0,0};
    int r = 0;
    for (; r + 8 <= rows; r += 8) {
        float4 v0 = *(const float4*)(base + (size_t)(r + 0) * H);
        float4 v1 = *(const float4*)(base + (size_t)(r + 1) * H);
        float4 v2 = *(const float4*)(base + (size_t)(r + 2) * H);
        float4 v3 = *(const float4*)(base + (size_t)(r + 3) * H);
        float4 v4 = *(const float4*)(base + (size_t)(r + 4) * H);
        float4 v5 = *(const float4*)(base + (size_t)(r + 5) * H);
        float4 v6 = *(const float4*)(base + (size_t)(r + 6) * H);
        float4 v7 = *(const float4*)(base + (size_t)(r + 7) * H);
        a0.x += v0.x; a0.y += v0.y; a0.z += v0.z; a0.w += v0.w;
        a1.x += v1.x; a1.y += v1.y; a1.z += v1.z; a1.w += v1.w;
        a2.x += v2.x; a2.y += v2.y; a2.z += v2.z; a2.w += v2.w;
        a3.x += v3.x; a3.y += v3.y; a3.z += v3.z; a3.w += v3.w;
        a4.x += v4.x; a4.y += v4.y; a4.z += v4.z; a4.w += v4.w;
        a5.x += v5.x; a5.y += v5.y; a5.z += v5.z; a5.w += v5.w;
        a6.x += v6.x; a6.y += v6.y; a6.z += v6.z; a6.w += v6.w;
        a7.x += v7.x; a7.y += v7.y; a7.z += v7.z; a7.w += v7.w;
    }
    for (; r < rows; ++r) {
        float4 v0 = *(const float4*)(base + (size_t)r * H);
        a0.x += v0.x; a0.y += v0.y; a0.z += v0.z; a0.w += v0.w;
    }
    float4 o;
    o.x = ((a0.x + a1.x) + (a2.x + a3.x)) + ((a4.x + a5.x) + (a6.x + a7.x));
    o.y = ((a0.y + a1.y) + (a2.y + a3.y)) + ((a4.y + a5.y) + (a6.y + a7.y));
    o.z = ((a0.z + a1.z) + (a2.z + a3.z)) + ((a4.z + a5.z) + (a6.z + a7.z));
    o.w = ((a0.w + a1.w) + (a2.w + a3.w)) + ((a4.w + a5.w) + (a6.w + a7.w));

    *(float4*)(part + ((size_t)bs * SLICES + sl) * H + t * 4) = o;
}

// Stage B: 512 blocks x 64 lanes, swizzled to the SAME XCD as the writers
// (bid2 % 8 == bs % 8) -> all 16 partial reads are local-L2 hits.
__global__ void k_reduce(const float* __restrict__ part, const int* __restrict__ vlen,
                         float* __restrict__ out, int H) {
    int bid = blockIdx.x;
    int x8 = bid & 7, inner = bid >> 3;  // inner in [0,64)
    int hc = inner & 3;
    int bs = ((inner >> 2) << 3) + x8;   // bs % 8 == x8
    int b = bs >> 4, s = bs & 15;
    int vl = vlen[b];
    int start = (s * vl) >> 4;
    int end   = ((s + 1) * vl) >> 4;
    int cnt = max(end - start, 1);
    int lane = threadIdx.x;
    int hoff = hc * 256 + lane * 4;

    float4 acc = {0,0,0,0};
    #pragma unroll
    for (int sl = 0; sl < SLICES; ++sl) {
        float4 v = *(const float4*)(part + ((size_t)bs * SLICES + sl) * H + hoff);
        acc.x += v.x; acc.y += v.y; acc.z += v.z; acc.w += v.w;
    }
    float scl = 1.0f / (float)cnt;       // empty segment -> partials 0 -> writes 0
    acc.x *= scl; acc.y *= scl; acc.z *= scl; acc.w *= scl;
    *(float4*)(out + (size_t)bs * H + hoff) = acc;
}

extern "C" void kernel_launch(void* const* d_in, const int* in_sizes, int n_in,
                              void* d_out, int out_size, void* d_ws, size_t ws_size,
                              hipStream_t stream) {
    const float* hs  = (const float*)d_in[0];
    const int* mask  = (const int*)d_in[1];
    int H = in_sizes[0] / in_sizes[1];          // 1024
    int B = out_size / (NSEG * (H + 1));        // 8
    int L = in_sizes[1] / B;                    // 4096

    float* seg_out  = (float*)d_out;
    float* mask_out = seg_out + (size_t)B * NSEG * H;
    int* vlen = (int*)d_ws;
    float* part = (float*)d_ws + 64;            // 256 B offset, 16B-aligned

    k_part<<<B * NSEG * SLICES, BTHR, 0, stream>>>(hs, mask, part, vlen, mask_out, L, H);
    k_reduce<<<B * NSEG * 4, 64, 0, stream>>>(part, vlen, seg_out, H);
}

// Round 10
// 19.757 us; speedup vs baseline: 20.5573x; 1.0471x over previous
//
#include <hip/hip_runtime.h>

#define NSEG   16
#define SLICES 8
#define BTHR   256

// Stage A: grid = B*NSEG*SLICES = 1024 blocks (4/CU), 256 thr, grain <= 32 rows.
// XCD swizzle: consecutive blockIdx round-robin XCDs on MI355X, so
// bid = xcd + 8*inner with bs%8 == xcd puts ALL 8 slices of segment bs on
// one XCD -> its partials stay in that XCD's L2 for stage B (matched swizzle).
// Each block redundantly block-reduces its batch's mask row (16 KB, L2-hot)
// -> vl, streams its row-slice, writes one 4 KB partial.
__global__ void __launch_bounds__(BTHR) k_part(
        const float* __restrict__ x, const int* __restrict__ mask,
        float* __restrict__ part, int* __restrict__ vlen,
        int L, int H) {
    int bid = blockIdx.x;
    int x8 = bid & 7, inner = bid >> 3;     // inner in [0,128)
    int sl = inner & (SLICES - 1);
    int bs = ((inner >> 3) << 3) + x8;      // bs % 8 == x8
    int b = bs >> 4, s = bs & 15;
    int t = threadIdx.x;                    // 0..255

    // ---- block-reduce mask row -> vl ----
    const int4* m4 = (const int4*)(mask + (size_t)b * L);
    int n4 = L >> 2;
    int acc = 0;
    for (int i = t; i < n4; i += BTHR) { int4 v = m4[i]; acc += v.x + v.y + v.z + v.w; }
    #pragma unroll
    for (int off = 32; off > 0; off >>= 1) acc += __shfl_down(acc, off, 64);
    __shared__ int sh[4];
    if ((t & 63) == 0) sh[t >> 6] = acc;
    __syncthreads();
    __shared__ int vsh;
    if (t == 0) {
        int v = sh[0] + sh[1] + sh[2] + sh[3];
        vsh = v;
        if (sl == 0 && s == 0) vlen[b] = v;
    }
    __syncthreads();
    int vl = vsh;

    int start = (s * vl) >> 4;                        // exact: s*vl < 2^24
    int end   = ((s + 1) * vl) >> 4;                  // s==15 -> exactly vl
    int n = (start < vl) ? max(end - start, 1) : 0;   // effective token count
    int i0 = (sl * n) / SLICES;
    int i1 = ((sl + 1) * n) / SLICES;
    int rows = i1 - i0;                               // <= 32

    // ---- stream rows [start+i0, start+i1), one 4 KB row per block-iter ----
    const float* base = x + ((size_t)b * L + start + i0) * H + t * 4;
    float4 a0 = {0,0,0,0}, a1 = {0,0,0,0}, a2 = {0,0,0,0}, a3 = {0,0,0,0};
    float4 a4 = {0,0,0,0}, a5 = {0,0,0,0}, a6 = {0,0,0,0}, a7 = {0,0,0,0};
    int r = 0;
    for (; r + 8 <= rows; r += 8) {
        float4 v0 = *(const float4*)(base + (size_t)(r + 0) * H);
        float4 v1 = *(const float4*)(base + (size_t)(r + 1) * H);
        float4 v2 = *(const float4*)(base + (size_t)(r + 2) * H);
        float4 v3 = *(const float4*)(base + (size_t)(r + 3) * H);
        float4 v4 = *(const float4*)(base + (size_t)(r + 4) * H);
        float4 v5 = *(const float4*)(base + (size_t)(r + 5) * H);
        float4 v6 = *(const float4*)(base + (size_t)(r + 6) * H);
        float4 v7 = *(const float4*)(base + (size_t)(r + 7) * H);
        a0.x += v0.x; a0.y += v0.y; a0.z += v0.z; a0.w += v0.w;
        a1.x += v1.x; a1.y += v1.y; a1.z += v1.z; a1.w += v1.w;
        a2.x += v2.x; a2.y += v2.y; a2.z += v2.z; a2.w += v2.w;
        a3.x += v3.x; a3.y += v3.y; a3.z += v3.z; a3.w += v3.w;
        a4.x += v4.x; a4.y += v4.y; a4.z += v4.z; a4.w += v4.w;
        a5.x += v5.x; a5.y += v5.y; a5.z += v5.z; a5.w += v5.w;
        a6.x += v6.x; a6.y += v6.y; a6.z += v6.z; a6.w += v6.w;
        a7.x += v7.x; a7.y += v7.y; a7.z += v7.z; a7.w += v7.w;
    }
    for (; r < rows; ++r) {
        float4 v0 = *(const float4*)(base + (size_t)r * H);
        a0.x += v0.x; a0.y += v0.y; a0.z += v0.z; a0.w += v0.w;
    }
    float4 o;
    o.x = ((a0.x + a1.x) + (a2.x + a3.x)) + ((a4.x + a5.x) + (a6.x + a7.x));
    o.y = ((a0.y + a1.y) + (a2.y + a3.y)) + ((a4.y + a5.y) + (a6.y + a7.y));
    o.z = ((a0.z + a1.z) + (a2.z + a3.z)) + ((a4.z + a5.z) + (a6.z + a7.z));
    o.w = ((a0.w + a1.w) + (a2.w + a3.w)) + ((a4.w + a5.w) + (a6.w + a7.w));

    *(float4*)(part + ((size_t)bs * SLICES + sl) * H + t * 4) = o;
}

// Stage B: one block per segment (128 blocks x 256 thr), thread t owns
// float4 column t of the full 1024-float row. Swizzled to the partials'
// XCD (bs%8 == bid&7): 8 contiguous 4 KB partial reads, local-L2.
// Also writes the seg_mask float (t==0).
__global__ void __launch_bounds__(BTHR) k_reduce(
        const float* __restrict__ part, const int* __restrict__ vlen,
        float* __restrict__ out, float* __restrict__ mout, int H) {
    int bid = blockIdx.x;
    int x8 = bid & 7, inner = bid >> 3;     // inner in [0,16)
    int bs = (inner << 3) + x8;             // bs % 8 == x8, bijective over [0,128)
    int b = bs >> 4, s = bs & 15;
    int vl = vlen[b];
    int start = (s * vl) >> 4;
    int end   = ((s + 1) * vl) >> 4;
    int cnt = max(end - start, 1);
    int t = threadIdx.x;
    int hoff = t * 4;                       // 256 thr x float4 = 1024 floats = H

    if (t == 0) mout[bs] = (start < vl) ? 1.0f : 0.0f;

    float4 acc = {0,0,0,0};
    #pragma unroll
    for (int sl = 0; sl < SLICES; ++sl) {
        float4 v = *(const float4*)(part + ((size_t)bs * SLICES + sl) * H + hoff);
        acc.x += v.x; acc.y += v.y; acc.z += v.z; acc.w += v.w;
    }
    float scl = 1.0f / (float)cnt;          // empty segment -> partials 0 -> 0
    acc.x *= scl; acc.y *= scl; acc.z *= scl; acc.w *= scl;
    *(float4*)(out + (size_t)bs * H + hoff) = acc;
}

extern "C" void kernel_launch(void* const* d_in, const int* in_sizes, int n_in,
                              void* d_out, int out_size, void* d_ws, size_t ws_size,
                              hipStream_t stream) {
    const float* hs  = (const float*)d_in[0];
    const int* mask  = (const int*)d_in[1];
    int H = in_sizes[0] / in_sizes[1];          // 1024
    int B = out_size / (NSEG * (H + 1));        // 8
    int L = in_sizes[1] / B;                    // 4096

    float* seg_out  = (float*)d_out;
    float* mask_out = seg_out + (size_t)B * NSEG * H;
    int* vlen = (int*)d_ws;
    float* part = (float*)d_ws + 64;            // 256 B offset, 16B-aligned

    k_part<<<B * NSEG * SLICES, BTHR, 0, stream>>>(hs, mask, part, vlen, L, H);
    k_reduce<<<B * NSEG, BTHR, 0, stream>>>(part, vlen, seg_out, mask_out, H);
}